// Round 8
// baseline (237.069 us; speedup 1.0000x reference)
//
#include <hip/hip_runtime.h>
#include <hip/hip_bf16.h>

typedef float f32x4 __attribute__((ext_vector_type(4)));
typedef float fvec4 __attribute__((ext_vector_type(4)));
typedef __bf16 bf16x8 __attribute__((ext_vector_type(8)));
typedef __bf16 bf16x2 __attribute__((ext_vector_type(2)));

__device__ inline float fexp2(float x) {
#if __has_builtin(__builtin_amdgcn_exp2f)
    return __builtin_amdgcn_exp2f(x);
#else
    return exp2f(x);
#endif
}

// packed f32x2 -> bf16x2 (single v_cvt_pk_bf16_f32 when available)
__device__ __forceinline__ bf16x2 pk_bf16(float a, float b) {
#if __has_builtin(__builtin_amdgcn_cvt_pk_bf16_f32)
    auto t = __builtin_amdgcn_cvt_pk_bf16_f32(a, b);
    return __builtin_bit_cast(bf16x2, t);
#else
    bf16x2 r; r[0] = (__bf16)a; r[1] = (__bf16)b; return r;
#endif
}

#define MFMA_BF16(a, b, c) __builtin_amdgcn_mfma_f32_16x16x32_bf16((a), (b), (c), 0, 0, 0)
#define SCHED_FENCE() __builtin_amdgcn_sched_barrier(0)

__device__ __forceinline__ void gl2lds16(const void* g, void* l) {
    __builtin_amdgcn_global_load_lds((const __attribute__((address_space(1))) void*)g,
                                     (__attribute__((address_space(3))) void*)l, 16, 0, 0);
}

// seg offsets (elements) inside compact Q/K/V buffers: [seg0 12x2048][seg1 12x4096][seg2 12x2048] x64d
#define SEG1OFF ((size_t)12 * 2048 * 64)
#define SEG2OFF ((size_t)12 * 6144 * 64)
#define QSCALE 0.18033688f  // SCALE * log2(e)

// ---------------- fused prep: x->bf16 cvt + both weight transposes ----------------
__global__ __launch_bounds__(256) void prep_kernel(
    const float* __restrict__ x, const float* __restrict__ Wqkv,
    const float* __restrict__ Wout, __bf16* __restrict__ xb,
    __bf16* __restrict__ WqkvT, __bf16* __restrict__ WoutT) {
    int bid = blockIdx.x, tid = threadIdx.x;
    if (bid < 3072) {
        int i = bid * 256 + tid;
        fvec4 a = ((const fvec4*)x)[2 * i];
        fvec4 b = ((const fvec4*)x)[2 * i + 1];
        bf16x8 o;
        o[0] = (__bf16)a[0]; o[1] = (__bf16)a[1]; o[2] = (__bf16)a[2]; o[3] = (__bf16)a[3];
        o[4] = (__bf16)b[0]; o[5] = (__bf16)b[1]; o[6] = (__bf16)b[2]; o[7] = (__bf16)b[3];
        ((bf16x8*)xb)[i] = o;
    } else if (bid < 3936) {
        int b = bid - 3072;
        int n = (b % 9) * 256 + tid;  // 0..2303
        int kg = b / 9;               // 0..95
        bf16x8 o;
#pragma unroll
        for (int j = 0; j < 8; j++) o[j] = (__bf16)Wqkv[(size_t)(kg * 8 + j) * 2304 + n];
        *(bf16x8*)&WqkvT[(size_t)n * 768 + kg * 8] = o;
    } else {
        int b = bid - 3936;
        int n = (b % 3) * 256 + tid;  // 0..767
        int kg = b / 3;               // 0..95
        bf16x8 o;
#pragma unroll
        for (int j = 0; j < 8; j++) o[j] = (__bf16)Wout[(size_t)(kg * 8 + j) * 768 + n];
        *(bf16x8*)&WoutT[(size_t)n * 768 + kg * 8] = o;
    }
}

// ---------------- QKV GEMM: [8192][768] x [2304][768]^T, BK=32, 3-4 blocks/CU -----
// BK 64->32 halves staging LDS (36KB incl. T overlay) -> 3-4 blocks/CU (was 2):
// 1152 blocks go from 2.25 rounds to <=1.5, and 12+ waves/CU hide staging latency.
// Tile 128x128 and the entire epilogue (incl. fused V transpose) unchanged.
__global__ __launch_bounds__(256, 3) void gemm_qkv_kernel(
    const __bf16* __restrict__ Ab, const __bf16* __restrict__ Bt,
    const float* __restrict__ bias,
    __bf16* __restrict__ Qc, __bf16* __restrict__ Kc, __bf16* __restrict__ Vt) {
    __shared__ __align__(16) char smem[36864];  // 2 x (A 8K + B 8K); T tile overlay
    __bf16* T = (__bf16*)smem;                  // [128][136] epilogue tile (34.8KB)
    int tid = threadIdx.x;
    int wave = tid >> 6, lane = tid & 63;
    int quad = lane >> 4, l15 = lane & 15;
    int bm = blockIdx.x * 128, bn = blockIdx.y * 128;
    int wm = (wave >> 1) * 64, wn = (wave & 1) * 64;
    // DMA slot decode: slot s = j*256+tid -> row s>>2, chunk (s&3)^(row&3)
    int rows_[2], chs_[2];
#pragma unroll
    for (int j = 0; j < 2; j++) {
        int s = j * 256 + tid;
        rows_[j] = s >> 2;
        chs_[j] = (s & 3) ^ (rows_[j] & 3);
    }
    f32x4 acc[4][4] = {};
    {   // prologue: buf0 <- k0=0
#pragma unroll
        for (int j = 0; j < 2; j++) {
            gl2lds16(&Ab[(size_t)(bm + rows_[j]) * 768 + chs_[j] * 8],
                     smem + j * 4096 + wave * 1024);
            gl2lds16(&Bt[(size_t)(bn + rows_[j]) * 768 + chs_[j] * 8],
                     smem + 8192 + j * 4096 + wave * 1024);
        }
    }
    for (int ki = 0; ki < 24; ki++) {
        __syncthreads();  // drains buf[ki&1]'s DMA; publishes to all waves
        int cur = ki & 1;
        if (ki + 1 < 24) {
            int nb = (cur ^ 1) * 16384;
            int k1 = (ki + 1) * 32;
#pragma unroll
            for (int j = 0; j < 2; j++) {
                gl2lds16(&Ab[(size_t)(bm + rows_[j]) * 768 + k1 + chs_[j] * 8],
                         smem + nb + j * 4096 + wave * 1024);
                gl2lds16(&Bt[(size_t)(bn + rows_[j]) * 768 + k1 + chs_[j] * 8],
                         smem + nb + 8192 + j * 4096 + wave * 1024);
            }
        }
        const __bf16* Al = (const __bf16*)(smem + cur * 16384);
        const __bf16* Bl = Al + 4096;
        bf16x8 af[4], bfr[4];
#pragma unroll
        for (int i = 0; i < 4; i++) {
            int row = wm + i * 16 + l15;
            af[i] = *(const bf16x8*)&Al[row * 32 + ((quad ^ (row & 3)) * 8)];
        }
#pragma unroll
        for (int j = 0; j < 4; j++) {
            int row = wn + j * 16 + l15;
            bfr[j] = *(const bf16x8*)&Bl[row * 32 + ((quad ^ (row & 3)) * 8)];
        }
#pragma unroll
        for (int i = 0; i < 4; i++)
#pragma unroll
            for (int j = 0; j < 4; j++)
                acc[i][j] = MFMA_BF16(af[i], bfr[j], acc[i][j]);
    }
    int which = blockIdx.y / 6;             // uniform: 0=Q 1=K 2=V
    int h0 = (blockIdx.y % 6) * 2;          // first head of this 128-col block
    float scl = which == 0 ? QSCALE : 1.0f;
    float bv[4];
#pragma unroll
    for (int j = 0; j < 4; j++) bv[j] = bias[bn + wn + j * 16 + l15];
    __syncthreads();  // done reading staging; T overlays it
#pragma unroll
    for (int i = 0; i < 4; i++)
#pragma unroll
        for (int j = 0; j < 4; j++) {
            int col = wn + j * 16 + l15;
#pragma unroll
            for (int r = 0; r < 4; r++) {
                int row = wm + i * 16 + quad * 4 + r;
                int ch = ((col >> 3) & 8) | (((col >> 3) & 7) ^ (row & 7));
                T[row * 136 + ch * 8 + (col & 7)] =
                    (__bf16)((acc[i][j][r] + bv[j]) * scl);
            }
        }
    __syncthreads();
    if (which < 2) {
        __bf16* dst = which == 0 ? Qc : Kc;
        int rr = tid >> 4;        // 0..15
        int c8 = tid & 15;        // 0..15
        int hh = c8 >> 3, d8 = c8 & 7;
        int h = h0 + hh;
        __bf16* p0 = dst + ((size_t)h * 2048 * 64) + d8 * 8;
        __bf16* p1 = dst + SEG1OFF + ((size_t)h * 4096 * 64) + d8 * 8;
        __bf16* p2 = dst + SEG2OFF + ((size_t)h * 2048 * 64) + d8 * 8;
#pragma unroll
        for (int pass = 0; pass < 8; pass++) {
            int row = pass * 16 + rr;
            int pos = bm + row;
            int ch = (c8 & 8) | ((c8 & 7) ^ (row & 7));
            bf16x8 v = *(const bf16x8*)&T[row * 136 + ch * 8];
            if (pos < 2048) *(bf16x8*)&p0[(size_t)pos * 64] = v;
            if (!(pos & 1)) *(bf16x8*)&p1[(size_t)(pos >> 1) * 64] = v;
            if (!(pos & 3)) *(bf16x8*)&p2[(size_t)(pos >> 2) * 64] = v;
        }
    } else {
        // fused V transpose: Vt[seg][head][d][t*64 + ck*8 + J] =
        //   V[spos = t*64 + perm(ck,J)][head*64+d], perm = (ck>>2)*32+(ck&3)*4+(J&3)+(J>>2)*16
        {
            __bf16* base1 = Vt + SEG1OFF;
#pragma unroll
            for (int it = 0; it < 4; it++) {
                int sid = it * 256 + tid;
                int hh = sid >> 9, ck = (sid >> 6) & 7, d = sid & 63;
                int col = hh * 64 + d;
                int kb = (ck >> 2) * 32 + (ck & 3) * 4;
                bf16x8 o;
#pragma unroll
                for (int J = 0; J < 8; J++) {
                    int k = kb + (J & 3) + (J >> 2) * 16;
                    int r = 2 * k;  // pos = 2*spos -> r = pos-bm = 2*k
                    int sc = ((col >> 3) & 8) | (((col >> 3) & 7) ^ (r & 7));
                    o[J] = T[r * 136 + sc * 8 + (col & 7)];
                }
                *(bf16x8*)&base1[(size_t)(h0 + hh) * 64 * 4096 + (size_t)d * 4096 +
                                 (bm >> 1) + ck * 8] = o;
            }
        }
        if (bm < 2048) {
#pragma unroll
            for (int it = 0; it < 8; it++) {
                int sid = it * 256 + tid;
                int tsub = sid >> 10, rest = sid & 1023;
                int hh = rest >> 9, ck = (rest >> 6) & 7, d = rest & 63;
                int col = hh * 64 + d;
                int kb = (ck >> 2) * 32 + (ck & 3) * 4;
                bf16x8 o;
#pragma unroll
                for (int J = 0; J < 8; J++) {
                    int k = kb + (J & 3) + (J >> 2) * 16;
                    int r = tsub * 64 + k;
                    int sc = ((col >> 3) & 8) | (((col >> 3) & 7) ^ (r & 7));
                    o[J] = T[r * 136 + sc * 8 + (col & 7)];
                }
                *(bf16x8*)&Vt[(size_t)(h0 + hh) * 64 * 2048 + (size_t)d * 2048 +
                              bm + tsub * 64 + ck * 8] = o;
            }
        }
        {
            __bf16* base2 = Vt + SEG2OFF;
            int ckoff = (bm & 128) ? 4 : 0;
            int rsub = (bm & 128) ? 128 : 0;
#pragma unroll
            for (int it = 0; it < 2; it++) {
                int sid = it * 256 + tid;
                int hh = sid >> 8, cki = (sid >> 6) & 3, d = sid & 63;
                int ck = cki + ckoff;
                int col = hh * 64 + d;
                int kb = (ck >> 2) * 32 + (ck & 3) * 4;
                bf16x8 o;
#pragma unroll
                for (int J = 0; J < 8; J++) {
                    int k = kb + (J & 3) + (J >> 2) * 16;
                    int r = 4 * k - rsub;  // pos = 4*spos -> r = 4k - (bm&128 ? 128 : 0)
                    int sc = ((col >> 3) & 8) | (((col >> 3) & 7) ^ (r & 7));
                    o[J] = T[r * 136 + sc * 8 + (col & 7)];
                }
                *(bf16x8*)&base2[(size_t)(h0 + hh) * 64 * 2048 + (size_t)d * 2048 +
                                 (bm >> 8) * 64 + ck * 8] = o;
            }
        }
    }
}

// ---------------- out-proj GEMM: 64x128 tiles, dbuf DMA-staged (768 blocks) -------
__global__ __launch_bounds__(256) void gemm_out_kernel(
    const __bf16* __restrict__ Ab, const __bf16* __restrict__ Bt,
    const float* __restrict__ bias, float* __restrict__ Co) {
    __shared__ __align__(16) char smem[49152];  // 2 x (A 8K + B 16K)
    int tid = threadIdx.x;
    int wave = tid >> 6, lane = tid & 63;
    int quad = lane >> 4, l15 = lane & 15;
    int bm = blockIdx.x * 64, bn = blockIdx.y * 128;
    int wn = wave * 32;
    int rowsA[2], chsA[2], rowsB[4], chsB[4];
#pragma unroll
    for (int j = 0; j < 2; j++) {
        int s = j * 256 + tid;
        rowsA[j] = s >> 3;
        chsA[j] = (s & 7) ^ (rowsA[j] & 7);
    }
#pragma unroll
    for (int j = 0; j < 4; j++) {
        int s = j * 256 + tid;
        rowsB[j] = s >> 3;
        chsB[j] = (s & 7) ^ (rowsB[j] & 7);
    }
    f32x4 acc[4][2] = {};
    {   // prologue: buf0 <- k0=0
#pragma unroll
        for (int j = 0; j < 2; j++)
            gl2lds16(&Ab[(size_t)(bm + rowsA[j]) * 768 + chsA[j] * 8],
                     smem + j * 4096 + wave * 1024);
#pragma unroll
        for (int j = 0; j < 4; j++)
            gl2lds16(&Bt[(size_t)(bn + rowsB[j]) * 768 + chsB[j] * 8],
                     smem + 8192 + j * 4096 + wave * 1024);
    }
    for (int ki = 0; ki < 12; ki++) {
        __syncthreads();
        int cur = ki & 1;
        if (ki + 1 < 12) {
            int nb = (cur ^ 1) * 24576;
            int k1 = (ki + 1) * 64;
#pragma unroll
            for (int j = 0; j < 2; j++)
                gl2lds16(&Ab[(size_t)(bm + rowsA[j]) * 768 + k1 + chsA[j] * 8],
                         smem + nb + j * 4096 + wave * 1024);
#pragma unroll
            for (int j = 0; j < 4; j++)
                gl2lds16(&Bt[(size_t)(bn + rowsB[j]) * 768 + k1 + chsB[j] * 8],
                         smem + nb + 8192 + j * 4096 + wave * 1024);
        }
        const __bf16* Al = (const __bf16*)(smem + cur * 24576);
        const __bf16* Bl = Al + 4096;
#pragma unroll
        for (int ks = 0; ks < 2; ks++) {
            bf16x8 af[4], bfr[2];
#pragma unroll
            for (int i = 0; i < 4; i++) {
                int row = i * 16 + l15;
                af[i] = *(const bf16x8*)&Al[row * 64 + (((ks * 4 + quad) ^ (row & 7)) * 8)];
            }
#pragma unroll
            for (int j = 0; j < 2; j++) {
                int row = wn + j * 16 + l15;
                bfr[j] = *(const bf16x8*)&Bl[row * 64 + (((ks * 4 + quad) ^ (row & 7)) * 8)];
            }
#pragma unroll
            for (int i = 0; i < 4; i++)
#pragma unroll
                for (int j = 0; j < 2; j++)
                    acc[i][j] = MFMA_BF16(af[i], bfr[j], acc[i][j]);
        }
    }
#pragma unroll
    for (int j = 0; j < 2; j++) {
        int c = bn + wn + j * 16 + l15;
        float bv = bias[c];
#pragma unroll
        for (int i = 0; i < 4; i++)
#pragma unroll
            for (int r = 0; r < 4; r++) {
                int row = bm + i * 16 + quad * 4 + r;
                Co[(size_t)row * 768 + c] = acc[i][j][r] + bv;
            }
    }
}

// ---------------- fused flash attention: S^T, no-max, kv-split, counted-vmcnt -----
// r3-exact (proven 85.6 us): 1920-block mixed grid (seg0/seg2 32-iter, seg1 4x16-
// iter kv-quarters) for scheduler backfill; head-major decode.
// Pipeline per iter: vmcnt(2)+barrier (K publish) ; prefetch ; QK^T(setprio) ;
// exp/cvt ; vmcnt(4)+barrier (V publish) ; PV(setprio).
__global__ __launch_bounds__(256, 2) void attn_kernel(
    const __bf16* __restrict__ Qcb, const __bf16* __restrict__ Kcb,
    const __bf16* __restrict__ Vtb,
    float* __restrict__ O0, float* __restrict__ O1a, float* __restrict__ O1b,
    float* __restrict__ O1c, float* __restrict__ O1d, float* __restrict__ O2,
    float* __restrict__ L0, float* __restrict__ L1a, float* __restrict__ L1b,
    float* __restrict__ L1c, float* __restrict__ L1d, float* __restrict__ L2) {
    __shared__ __bf16 Kl[2 * 4096];
    __shared__ __bf16 Vl[2 * 4096];
    int bid = blockIdx.x;
    int seg, piece = 0, head, qt, Lc, iters;
    if (bid < 192)      { seg = 0; head = bid >> 4; qt = bid & 15; Lc = 2048; iters = 32; }
    else if (bid < 384) { int i = bid - 192; seg = 2; head = i >> 4; qt = i & 15; Lc = 2048; iters = 32; }
    else                { int i = bid - 384; seg = 1; head = i >> 7; int r = i & 127;
                          qt = r >> 2; piece = r & 3; Lc = 4096; iters = 16; }
    size_t soff = seg == 0 ? 0 : (seg == 1 ? SEG1OFF : SEG2OFF);
    const __bf16* Qh = Qcb + soff + (size_t)head * Lc * 64;
    const __bf16* Kh = Kcb + soff + (size_t)head * Lc * 64;
    const __bf16* Vh = Vtb + soff + (size_t)head * 64 * Lc;
    float* Ob;
    float* Lb;
    if (seg == 0)      { Ob = O0; Lb = L0 + head * 2048; }
    else if (seg == 2) { Ob = O2; Lb = L2 + head * 2048; }
    else {
        Ob = piece == 0 ? O1a : (piece == 1 ? O1b : (piece == 2 ? O1c : O1d));
        Lb = (piece == 0 ? L1a : (piece == 1 ? L1b : (piece == 2 ? L1c : L1d))) + head * 4096;
    }
    int kvb = piece * 16;
    int tid = threadIdx.x, wave = tid >> 6, lane = tid & 63;
    int quad = lane >> 4, l15 = lane & 15;
    bf16x8 qf[2][2];
#pragma unroll
    for (int qg = 0; qg < 2; qg++) {
        size_t qpos = (size_t)(qt * 128 + wave * 32 + qg * 16 + l15);
        qf[qg][0] = *(const bf16x8*)&Qh[qpos * 64 + quad * 8];
        qf[qg][1] = *(const bf16x8*)&Qh[qpos * 64 + 32 + quad * 8];
    }
    f32x4 o[2][4] = {};
    f32x4 lacc[2] = {};
    bf16x8 ones;
#pragma unroll
    for (int j = 0; j < 8; j++) ones[j] = (__bf16)1.0f;
    int kv0 = tid >> 3, cl0 = tid & 7;
    int kdb0 = cl0 ^ (kv0 & 7);
    int kv1 = kv0 + 32, kdb1 = cl0 ^ (kv1 & 7);
    char* KlB = (char*)Kl;
    char* VlB = (char*)Vl;
    int swz = l15 & 7;
    {   // prologue: buffer 0 <- tile kvb; order K,K then V,V (vmcnt ledger)
        int t0 = kvb * 64;
        gl2lds16(&Kh[(size_t)(t0 + kv0) * 64 + kdb0 * 8], KlB + wave * 1024);
        gl2lds16(&Kh[(size_t)(t0 + kv1) * 64 + kdb1 * 8], KlB + 4096 + wave * 1024);
        SCHED_FENCE();
        gl2lds16(&Vh[(size_t)kv0 * Lc + t0 + kdb0 * 8], VlB + wave * 1024);
        gl2lds16(&Vh[(size_t)kv1 * Lc + t0 + kdb1 * 8], VlB + 4096 + wave * 1024);
    }
    for (int nt = 0; nt < iters; nt++) {
        int cur = nt & 1;
        // K-publish: oldest 2 outstanding (this tile's K) must land; V + prefetch fly on
        SCHED_FENCE();
        asm volatile("s_waitcnt vmcnt(2)" ::: "memory");
        __builtin_amdgcn_s_barrier();
        SCHED_FENCE();
        if (nt + 1 < iters) {
            int nb = 8192 * (cur ^ 1);
            int t1 = (kvb + nt + 1) * 64;
            gl2lds16(&Kh[(size_t)(t1 + kv0) * 64 + kdb0 * 8], KlB + nb + wave * 1024);
            gl2lds16(&Kh[(size_t)(t1 + kv1) * 64 + kdb1 * 8], KlB + nb + 4096 + wave * 1024);
            SCHED_FENCE();
            gl2lds16(&Vh[(size_t)kv0 * Lc + t1 + kdb0 * 8], VlB + nb + wave * 1024);
            gl2lds16(&Vh[(size_t)kv1 * Lc + t1 + kdb1 * 8], VlB + nb + 4096 + wave * 1024);
        }
        SCHED_FENCE();
        const __bf16* Kt = Kl + cur * 4096;
        const __bf16* Vt_ = Vl + cur * 4096;
        f32x4 sarr[4][2];
        __builtin_amdgcn_s_setprio(1);
#pragma unroll
        for (int c = 0; c < 4; c++) {
            int krow = (c * 16 + l15) * 64;
            bf16x8 kf0 = *(const bf16x8*)&Kt[krow + ((quad ^ swz) * 8)];
            bf16x8 kf1 = *(const bf16x8*)&Kt[krow + (((4 + quad) ^ swz) * 8)];
#pragma unroll
            for (int qg = 0; qg < 2; qg++) {
                f32x4 z = {};
                z = MFMA_BF16(kf0, qf[qg][0], z);
                sarr[c][qg] = MFMA_BF16(kf1, qf[qg][1], z);
            }
        }
        __builtin_amdgcn_s_setprio(0);
        union { bf16x8 v8; bf16x2 v2[4]; } pf8[2][2];
#pragma unroll
        for (int qg = 0; qg < 2; qg++)
#pragma unroll
            for (int c = 0; c < 4; c++) {
                float p0 = fexp2(sarr[c][qg][0]);
                float p1 = fexp2(sarr[c][qg][1]);
                float p2 = fexp2(sarr[c][qg][2]);
                float p3 = fexp2(sarr[c][qg][3]);
                pf8[qg][c >> 1].v2[(c & 1) * 2 + 0] = pk_bf16(p0, p1);
                pf8[qg][c >> 1].v2[(c & 1) * 2 + 1] = pk_bf16(p2, p3);
            }
        // V-publish: drain this tile's V; prefetched K/V for t+1 stay in flight
        SCHED_FENCE();
        if (nt + 1 < iters) {
            asm volatile("s_waitcnt vmcnt(4)" ::: "memory");
        } else {
            asm volatile("s_waitcnt vmcnt(0)" ::: "memory");
        }
        __builtin_amdgcn_s_barrier();
        SCHED_FENCE();
        __builtin_amdgcn_s_setprio(1);
#pragma unroll
        for (int u = 0; u < 2; u++) {
#pragma unroll
            for (int ds = 0; ds < 4; ds++) {
                int d = ds * 16 + l15;
                bf16x8 vf = *(const bf16x8*)&Vt_[d * 64 + (((u * 4 + quad) ^ swz) * 8)];
                o[0][ds] = MFMA_BF16(vf, pf8[0][u].v8, o[0][ds]);
                o[1][ds] = MFMA_BF16(vf, pf8[1][u].v8, o[1][ds]);
            }
            lacc[0] = MFMA_BF16(ones, pf8[0][u].v8, lacc[0]);
            lacc[1] = MFMA_BF16(ones, pf8[1][u].v8, lacc[1]);
        }
        __builtin_amdgcn_s_setprio(0);
    }
#pragma unroll
    for (int qg = 0; qg < 2; qg++) {
        float l = lacc[qg][0];  // rows redundant: every lane has its column's sum
        int pos = qt * 128 + wave * 32 + qg * 16 + l15;
        float* orow = Ob + (size_t)pos * 768 + head * 64;
#pragma unroll
        for (int ds = 0; ds < 4; ds++)
            *(f32x4*)&orow[ds * 16 + quad * 4] = o[qg][ds];
        if (lane < 16) Lb[qt * 128 + wave * 32 + qg * 16 + lane] = l;
    }
}

// ---------------- combine: attnF[q][768] = (1/3) * sum_seg O_seg/l_seg, bf16 -------
__global__ __launch_bounds__(256) void combine_kernel(
    const float* __restrict__ O0, const float* __restrict__ O1a,
    const float* __restrict__ O1b, const float* __restrict__ O1c,
    const float* __restrict__ O1d, const float* __restrict__ O2,
    const float* __restrict__ L0, const float* __restrict__ L1a,
    const float* __restrict__ L1b, const float* __restrict__ L1c,
    const float* __restrict__ L1d, const float* __restrict__ L2,
    __bf16* __restrict__ attnF) {
    int g = blockIdx.x * 256 + threadIdx.x;  // 8192*96
    int q = g / 96;
    int cs = (g - q * 96) * 8;
    int head = cs >> 6;
    f32x4 a0 = {}, a1 = {};
    if (q < 2048) {
        float inv = 1.0f / L0[head * 2048 + q];
        const f32x4* p = (const f32x4*)&O0[(size_t)q * 768 + cs];
        a0 += p[0] * inv; a1 += p[1] * inv;
    }
    if (!(q & 1)) {
        int p1 = q >> 1;
        int li = head * 4096 + p1;
        float inv = 1.0f / (L1a[li] + L1b[li] + L1c[li] + L1d[li]);
        size_t ro = (size_t)p1 * 768 + cs;
        const f32x4* pa = (const f32x4*)&O1a[ro];
        const f32x4* pb = (const f32x4*)&O1b[ro];
        const f32x4* pc = (const f32x4*)&O1c[ro];
        const f32x4* pd = (const f32x4*)&O1d[ro];
        a0 += ((pa[0] + pb[0]) + (pc[0] + pd[0])) * inv;
        a1 += ((pa[1] + pb[1]) + (pc[1] + pd[1])) * inv;
    }
    if (!(q & 3)) {
        int p2 = q >> 2;
        float inv = 1.0f / L2[head * 2048 + p2];
        const f32x4* p = (const f32x4*)&O2[(size_t)p2 * 768 + cs];
        a0 += p[0] * inv; a1 += p[1] * inv;
    }
    const float third = 1.0f / 3.0f;
    bf16x8 ov;
    ov[0] = (__bf16)(a0[0] * third); ov[1] = (__bf16)(a0[1] * third);
    ov[2] = (__bf16)(a0[2] * third); ov[3] = (__bf16)(a0[3] * third);
    ov[4] = (__bf16)(a1[0] * third); ov[5] = (__bf16)(a1[1] * third);
    ov[6] = (__bf16)(a1[2] * third); ov[7] = (__bf16)(a1[3] * third);
    *(bf16x8*)&attnF[(size_t)q * 768 + cs] = ov;
}

extern "C" void kernel_launch(void* const* d_in, const int* in_sizes, int n_in,
                              void* d_out, int out_size, void* d_ws, size_t ws_size,
                              hipStream_t stream) {
    const float* x    = (const float*)d_in[0];
    const float* Wqkv = (const float*)d_in[1];
    const float* bqkv = (const float*)d_in[2];
    const float* Wout = (const float*)d_in[3];
    const float* bout = (const float*)d_in[4];
    float* out = (float*)d_out;
    (void)in_sizes; (void)n_in; (void)out_size; (void)ws_size;

    char* ws = (char*)d_ws;
    size_t off = 0;
    auto take = [&](size_t bytes) -> void* {
        void* p = ws + off;
        off += (bytes + 255) & ~(size_t)255;
        return p;
    };
    const size_t QKV_ELEMS = (size_t)12 * 8192 * 64;  // compact seg-major total
    __bf16* xb    = (__bf16*)take((size_t)8192 * 768 * 2);  // dead after gemm0 -> O0|O2
    __bf16* WqkvT = (__bf16*)take((size_t)2304 * 768 * 2);
    __bf16* WoutT = (__bf16*)take((size_t)768 * 768 * 2);
    __bf16* Qc    = (__bf16*)take(QKV_ELEMS * 2);           // attnF alias after attn
    __bf16* Kc    = (__bf16*)take(QKV_ELEMS * 2);
    __bf16* Vc    = (__bf16*)take(QKV_ELEMS * 2);           // unused pre-attn -> O1d
    __bf16* Vt    = (__bf16*)take(QKV_ELEMS * 2);
    float*  O1a   = (float*)take((size_t)4096 * 768 * 4);
    float*  O1b   = (float*)take((size_t)4096 * 768 * 4);
    float*  O1c   = (float*)take((size_t)4096 * 768 * 4);
    float*  L0    = (float*)take((size_t)12 * 2048 * 4);
    float*  L1a   = (float*)take((size_t)12 * 4096 * 4);
    float*  L1b   = (float*)take((size_t)12 * 4096 * 4);
    float*  L1c   = (float*)take((size_t)12 * 4096 * 4);
    float*  L1d   = (float*)take((size_t)12 * 4096 * 4);
    float*  L2    = (float*)take((size_t)12 * 2048 * 4);
    float*  O0    = (float*)xb;                 // 2048*768 f32 = 6.29 MB
    float*  O2    = O0 + (size_t)2048 * 768;    // next 6.29 MB (xb is 12.58 MB)
    float*  O1d   = (float*)Vc;                 // 4096*768 f32 = 12.58 MB = |Vc|
    __bf16* attnF = Qc;                         // Qc dead after attn_kernel

    prep_kernel<<<4224, 256, 0, stream>>>(x, Wqkv, Wout, xb, WqkvT, WoutT);
    gemm_qkv_kernel<<<dim3(64, 18), 256, 0, stream>>>(xb, WqkvT, bqkv, Qc, Kc, Vt);
    attn_kernel<<<1920, 256, 0, stream>>>(Qc, Kc, Vt, O0, O1a, O1b, O1c, O1d, O2,
                                          L0, L1a, L1b, L1c, L1d, L2);
    combine_kernel<<<3072, 256, 0, stream>>>(O0, O1a, O1b, O1c, O1d, O2,
                                             L0, L1a, L1b, L1c, L1d, L2, attnF);
    gemm_out_kernel<<<dim3(128, 6), 256, 0, stream>>>(attnF, WoutT, bout, out);
}

// Round 9
// 230.753 us; speedup vs baseline: 1.0274x; 1.0274x over previous
//
#include <hip/hip_runtime.h>
#include <hip/hip_bf16.h>

typedef float f32x4 __attribute__((ext_vector_type(4)));
typedef float fvec4 __attribute__((ext_vector_type(4)));
typedef __bf16 bf16x8 __attribute__((ext_vector_type(8)));
typedef __bf16 bf16x2 __attribute__((ext_vector_type(2)));

__device__ inline float fexp2(float x) {
#if __has_builtin(__builtin_amdgcn_exp2f)
    return __builtin_amdgcn_exp2f(x);
#else
    return exp2f(x);
#endif
}

// packed f32x2 -> bf16x2 (single v_cvt_pk_bf16_f32 when available)
__device__ __forceinline__ bf16x2 pk_bf16(float a, float b) {
#if __has_builtin(__builtin_amdgcn_cvt_pk_bf16_f32)
    auto t = __builtin_amdgcn_cvt_pk_bf16_f32(a, b);
    return __builtin_bit_cast(bf16x2, t);
#else
    bf16x2 r; r[0] = (__bf16)a; r[1] = (__bf16)b; return r;
#endif
}

#define MFMA_BF16(a, b, c) __builtin_amdgcn_mfma_f32_16x16x32_bf16((a), (b), (c), 0, 0, 0)
#define SCHED_FENCE() __builtin_amdgcn_sched_barrier(0)

__device__ __forceinline__ void gl2lds16(const void* g, void* l) {
    __builtin_amdgcn_global_load_lds((const __attribute__((address_space(1))) void*)g,
                                     (__attribute__((address_space(3))) void*)l, 16, 0, 0);
}

// seg offsets (elements) inside compact Q/K/V buffers: [seg0 12x2048][seg1 12x4096][seg2 12x2048] x64d
#define SEG1OFF ((size_t)12 * 2048 * 64)
#define SEG2OFF ((size_t)12 * 6144 * 64)
#define QSCALE 0.18033688f  // SCALE * log2(e)

// ---------------- fused prep: x->bf16 cvt + both weight transposes ----------------
__global__ __launch_bounds__(256) void prep_kernel(
    const float* __restrict__ x, const float* __restrict__ Wqkv,
    const float* __restrict__ Wout, __bf16* __restrict__ xb,
    __bf16* __restrict__ WqkvT, __bf16* __restrict__ WoutT) {
    int bid = blockIdx.x, tid = threadIdx.x;
    if (bid < 3072) {
        int i = bid * 256 + tid;
        fvec4 a = ((const fvec4*)x)[2 * i];
        fvec4 b = ((const fvec4*)x)[2 * i + 1];
        bf16x8 o;
        o[0] = (__bf16)a[0]; o[1] = (__bf16)a[1]; o[2] = (__bf16)a[2]; o[3] = (__bf16)a[3];
        o[4] = (__bf16)b[0]; o[5] = (__bf16)b[1]; o[6] = (__bf16)b[2]; o[7] = (__bf16)b[3];
        ((bf16x8*)xb)[i] = o;
    } else if (bid < 3936) {
        int b = bid - 3072;
        int n = (b % 9) * 256 + tid;  // 0..2303
        int kg = b / 9;               // 0..95
        bf16x8 o;
#pragma unroll
        for (int j = 0; j < 8; j++) o[j] = (__bf16)Wqkv[(size_t)(kg * 8 + j) * 2304 + n];
        *(bf16x8*)&WqkvT[(size_t)n * 768 + kg * 8] = o;
    } else {
        int b = bid - 3936;
        int n = (b % 3) * 256 + tid;  // 0..767
        int kg = b / 3;               // 0..95
        bf16x8 o;
#pragma unroll
        for (int j = 0; j < 8; j++) o[j] = (__bf16)Wout[(size_t)(kg * 8 + j) * 768 + n];
        *(bf16x8*)&WoutT[(size_t)n * 768 + kg * 8] = o;
    }
}

// ---------------- QKV GEMM: [8192][768] x [2304][768]^T, dbuf DMA-staged ----------
// V blocks (which==2) write Vt DIRECTLY in vtrans's [seg][head][64][Lc] MFMA-k
// order (transpose fused in epilogue; vtrans kernel + Vc round-trip eliminated).
__global__ __launch_bounds__(256, 2) void gemm_qkv_kernel(
    const __bf16* __restrict__ Ab, const __bf16* __restrict__ Bt,
    const float* __restrict__ bias,
    __bf16* __restrict__ Qc, __bf16* __restrict__ Kc, __bf16* __restrict__ Vt) {
    __shared__ __align__(16) char smem[65536];  // 2 x (A 16K + B 16K); T tile reuse
    __bf16* T = (__bf16*)smem;                  // [128][136] epilogue tile
    int tid = threadIdx.x;
    int wave = tid >> 6, lane = tid & 63;
    int quad = lane >> 4, l15 = lane & 15;
    int bm = blockIdx.x * 128, bn = blockIdx.y * 128;
    int wm = (wave >> 1) * 64, wn = (wave & 1) * 64;
    int swzA = tid & 7;
    int rows_[4], chs_[4];
#pragma unroll
    for (int j = 0; j < 4; j++) {
        int s = j * 256 + tid;
        rows_[j] = s >> 3;
        chs_[j] = swzA ^ (rows_[j] & 7);
    }
    f32x4 acc[4][4] = {};
    {   // prologue: buf0 <- k0=0
#pragma unroll
        for (int j = 0; j < 4; j++) {
            gl2lds16(&Ab[(size_t)(bm + rows_[j]) * 768 + chs_[j] * 8],
                     smem + j * 4096 + wave * 1024);
            gl2lds16(&Bt[(size_t)(bn + rows_[j]) * 768 + chs_[j] * 8],
                     smem + 16384 + j * 4096 + wave * 1024);
        }
    }
    for (int ki = 0; ki < 12; ki++) {
        __syncthreads();  // drains buf[ki&1]'s DMA; publishes to all waves
        int cur = ki & 1;
        if (ki + 1 < 12) {
            int nb = (cur ^ 1) * 32768;
            int k1 = (ki + 1) * 64;
#pragma unroll
            for (int j = 0; j < 4; j++) {
                gl2lds16(&Ab[(size_t)(bm + rows_[j]) * 768 + k1 + chs_[j] * 8],
                         smem + nb + j * 4096 + wave * 1024);
                gl2lds16(&Bt[(size_t)(bn + rows_[j]) * 768 + k1 + chs_[j] * 8],
                         smem + nb + 16384 + j * 4096 + wave * 1024);
            }
        }
        const __bf16* Al = (const __bf16*)(smem + cur * 32768);
        const __bf16* Bl = Al + 8192;
#pragma unroll
        for (int ks = 0; ks < 2; ks++) {
            bf16x8 af[4], bfr[4];
#pragma unroll
            for (int i = 0; i < 4; i++) {
                int row = wm + i * 16 + l15;
                af[i] = *(const bf16x8*)&Al[row * 64 + (((ks * 4 + quad) ^ (row & 7)) * 8)];
            }
#pragma unroll
            for (int j = 0; j < 4; j++) {
                int row = wn + j * 16 + l15;
                bfr[j] = *(const bf16x8*)&Bl[row * 64 + (((ks * 4 + quad) ^ (row & 7)) * 8)];
            }
#pragma unroll
            for (int i = 0; i < 4; i++)
#pragma unroll
                for (int j = 0; j < 4; j++)
                    acc[i][j] = MFMA_BF16(af[i], bfr[j], acc[i][j]);
        }
    }
    int which = blockIdx.y / 6;             // uniform: 0=Q 1=K 2=V
    int h0 = (blockIdx.y % 6) * 2;          // first head of this 128-col block
    float scl = which == 0 ? QSCALE : 1.0f;
    float bv[4];
#pragma unroll
    for (int j = 0; j < 4; j++) bv[j] = bias[bn + wn + j * 16 + l15];
    __syncthreads();  // done reading staging; T overlays it
#pragma unroll
    for (int i = 0; i < 4; i++)
#pragma unroll
        for (int j = 0; j < 4; j++) {
            int col = wn + j * 16 + l15;
#pragma unroll
            for (int r = 0; r < 4; r++) {
                int row = wm + i * 16 + quad * 4 + r;
                int ch = ((col >> 3) & 8) | (((col >> 3) & 7) ^ (row & 7));
                T[row * 136 + ch * 8 + (col & 7)] =
                    (__bf16)((acc[i][j][r] + bv[j]) * scl);
            }
        }
    __syncthreads();
    if (which < 2) {
        __bf16* dst = which == 0 ? Qc : Kc;
        int rr = tid >> 4;        // 0..15
        int c8 = tid & 15;        // 0..15
        int hh = c8 >> 3, d8 = c8 & 7;
        int h = h0 + hh;
        __bf16* p0 = dst + ((size_t)h * 2048 * 64) + d8 * 8;
        __bf16* p1 = dst + SEG1OFF + ((size_t)h * 4096 * 64) + d8 * 8;
        __bf16* p2 = dst + SEG2OFF + ((size_t)h * 2048 * 64) + d8 * 8;
#pragma unroll
        for (int pass = 0; pass < 8; pass++) {
            int row = pass * 16 + rr;
            int pos = bm + row;
            int ch = (c8 & 8) | ((c8 & 7) ^ (row & 7));
            bf16x8 v = *(const bf16x8*)&T[row * 136 + ch * 8];
            if (pos < 2048) *(bf16x8*)&p0[(size_t)pos * 64] = v;
            if (!(pos & 1)) *(bf16x8*)&p1[(size_t)(pos >> 1) * 64] = v;
            if (!(pos & 3)) *(bf16x8*)&p2[(size_t)(pos >> 2) * 64] = v;
        }
    } else {
        // fused V transpose: Vt[seg][head][d][t*64 + ck*8 + J] =
        //   V[spos = t*64 + perm(ck,J)][head*64+d], perm = (ck>>2)*32+(ck&3)*4+(J&3)+(J>>2)*16
        {
            __bf16* base1 = Vt + SEG1OFF;
#pragma unroll
            for (int it = 0; it < 4; it++) {
                int sid = it * 256 + tid;
                int hh = sid >> 9, ck = (sid >> 6) & 7, d = sid & 63;
                int col = hh * 64 + d;
                int kb = (ck >> 2) * 32 + (ck & 3) * 4;
                bf16x8 o;
#pragma unroll
                for (int J = 0; J < 8; J++) {
                    int k = kb + (J & 3) + (J >> 2) * 16;
                    int r = 2 * k;  // pos = 2*spos -> r = pos-bm = 2*k
                    int sc = ((col >> 3) & 8) | (((col >> 3) & 7) ^ (r & 7));
                    o[J] = T[r * 136 + sc * 8 + (col & 7)];
                }
                *(bf16x8*)&base1[(size_t)(h0 + hh) * 64 * 4096 + (size_t)d * 4096 +
                                 (bm >> 1) + ck * 8] = o;
            }
        }
        if (bm < 2048) {
#pragma unroll
            for (int it = 0; it < 8; it++) {
                int sid = it * 256 + tid;
                int tsub = sid >> 10, rest = sid & 1023;
                int hh = rest >> 9, ck = (rest >> 6) & 7, d = rest & 63;
                int col = hh * 64 + d;
                int kb = (ck >> 2) * 32 + (ck & 3) * 4;
                bf16x8 o;
#pragma unroll
                for (int J = 0; J < 8; J++) {
                    int k = kb + (J & 3) + (J >> 2) * 16;
                    int r = tsub * 64 + k;
                    int sc = ((col >> 3) & 8) | (((col >> 3) & 7) ^ (r & 7));
                    o[J] = T[r * 136 + sc * 8 + (col & 7)];
                }
                *(bf16x8*)&Vt[(size_t)(h0 + hh) * 64 * 2048 + (size_t)d * 2048 +
                              bm + tsub * 64 + ck * 8] = o;
            }
        }
        {
            __bf16* base2 = Vt + SEG2OFF;
            int ckoff = (bm & 128) ? 4 : 0;
            int rsub = (bm & 128) ? 128 : 0;
#pragma unroll
            for (int it = 0; it < 2; it++) {
                int sid = it * 256 + tid;
                int hh = sid >> 8, cki = (sid >> 6) & 3, d = sid & 63;
                int ck = cki + ckoff;
                int col = hh * 64 + d;
                int kb = (ck >> 2) * 32 + (ck & 3) * 4;
                bf16x8 o;
#pragma unroll
                for (int J = 0; J < 8; J++) {
                    int k = kb + (J & 3) + (J >> 2) * 16;
                    int r = 4 * k - rsub;  // pos = 4*spos -> r = 4k - (bm&128 ? 128 : 0)
                    int sc = ((col >> 3) & 8) | (((col >> 3) & 7) ^ (r & 7));
                    o[J] = T[r * 136 + sc * 8 + (col & 7)];
                }
                *(bf16x8*)&base2[(size_t)(h0 + hh) * 64 * 2048 + (size_t)d * 2048 +
                                 (bm >> 8) * 64 + ck * 8] = o;
            }
        }
    }
}

// ---------------- out-proj GEMM: 64x128 tiles, dbuf DMA-staged (768 blocks) -------
__global__ __launch_bounds__(256) void gemm_out_kernel(
    const __bf16* __restrict__ Ab, const __bf16* __restrict__ Bt,
    const float* __restrict__ bias, float* __restrict__ Co) {
    __shared__ __align__(16) char smem[49152];  // 2 x (A 8K + B 16K)
    int tid = threadIdx.x;
    int wave = tid >> 6, lane = tid & 63;
    int quad = lane >> 4, l15 = lane & 15;
    int bm = blockIdx.x * 64, bn = blockIdx.y * 128;
    int wn = wave * 32;
    int rowsA[2], chsA[2], rowsB[4], chsB[4];
#pragma unroll
    for (int j = 0; j < 2; j++) {
        int s = j * 256 + tid;
        rowsA[j] = s >> 3;
        chsA[j] = (s & 7) ^ (rowsA[j] & 7);
    }
#pragma unroll
    for (int j = 0; j < 4; j++) {
        int s = j * 256 + tid;
        rowsB[j] = s >> 3;
        chsB[j] = (s & 7) ^ (rowsB[j] & 7);
    }
    f32x4 acc[4][2] = {};
    {   // prologue: buf0 <- k0=0
#pragma unroll
        for (int j = 0; j < 2; j++)
            gl2lds16(&Ab[(size_t)(bm + rowsA[j]) * 768 + chsA[j] * 8],
                     smem + j * 4096 + wave * 1024);
#pragma unroll
        for (int j = 0; j < 4; j++)
            gl2lds16(&Bt[(size_t)(bn + rowsB[j]) * 768 + chsB[j] * 8],
                     smem + 8192 + j * 4096 + wave * 1024);
    }
    for (int ki = 0; ki < 12; ki++) {
        __syncthreads();
        int cur = ki & 1;
        if (ki + 1 < 12) {
            int nb = (cur ^ 1) * 24576;
            int k1 = (ki + 1) * 64;
#pragma unroll
            for (int j = 0; j < 2; j++)
                gl2lds16(&Ab[(size_t)(bm + rowsA[j]) * 768 + k1 + chsA[j] * 8],
                         smem + nb + j * 4096 + wave * 1024);
#pragma unroll
            for (int j = 0; j < 4; j++)
                gl2lds16(&Bt[(size_t)(bn + rowsB[j]) * 768 + k1 + chsB[j] * 8],
                         smem + nb + 8192 + j * 4096 + wave * 1024);
        }
        const __bf16* Al = (const __bf16*)(smem + cur * 24576);
        const __bf16* Bl = Al + 4096;
#pragma unroll
        for (int ks = 0; ks < 2; ks++) {
            bf16x8 af[4], bfr[2];
#pragma unroll
            for (int i = 0; i < 4; i++) {
                int row = i * 16 + l15;
                af[i] = *(const bf16x8*)&Al[row * 64 + (((ks * 4 + quad) ^ (row & 7)) * 8)];
            }
#pragma unroll
            for (int j = 0; j < 2; j++) {
                int row = wn + j * 16 + l15;
                bfr[j] = *(const bf16x8*)&Bl[row * 64 + (((ks * 4 + quad) ^ (row & 7)) * 8)];
            }
#pragma unroll
            for (int i = 0; i < 4; i++)
#pragma unroll
                for (int j = 0; j < 2; j++)
                    acc[i][j] = MFMA_BF16(af[i], bfr[j], acc[i][j]);
        }
    }
#pragma unroll
    for (int j = 0; j < 2; j++) {
        int c = bn + wn + j * 16 + l15;
        float bv = bias[c];
#pragma unroll
        for (int i = 0; i < 4; i++)
#pragma unroll
            for (int r = 0; r < 4; r++) {
                int row = bm + i * 16 + quad * 4 + r;
                Co[(size_t)row * 768 + c] = acc[i][j][r] + bv;
            }
    }
}

// ---------------- fused flash attention: S^T, no-max, kv-split, counted-vmcnt -----
// r3-exact (proven 85.6 us): 1920-block mixed grid (seg0/seg2 32-iter, seg1 4x16-
// iter kv-quarters) for scheduler backfill; head-major decode.
// Pipeline per iter: vmcnt(2)+barrier (K publish) ; prefetch ; QK^T(setprio) ;
// exp/cvt ; vmcnt(4)+barrier (V publish) ; PV(setprio).
__global__ __launch_bounds__(256, 2) void attn_kernel(
    const __bf16* __restrict__ Qcb, const __bf16* __restrict__ Kcb,
    const __bf16* __restrict__ Vtb,
    float* __restrict__ O0, float* __restrict__ O1a, float* __restrict__ O1b,
    float* __restrict__ O1c, float* __restrict__ O1d, float* __restrict__ O2,
    float* __restrict__ L0, float* __restrict__ L1a, float* __restrict__ L1b,
    float* __restrict__ L1c, float* __restrict__ L1d, float* __restrict__ L2) {
    __shared__ __bf16 Kl[2 * 4096];
    __shared__ __bf16 Vl[2 * 4096];
    int bid = blockIdx.x;
    int seg, piece = 0, head, qt, Lc, iters;
    if (bid < 192)      { seg = 0; head = bid >> 4; qt = bid & 15; Lc = 2048; iters = 32; }
    else if (bid < 384) { int i = bid - 192; seg = 2; head = i >> 4; qt = i & 15; Lc = 2048; iters = 32; }
    else                { int i = bid - 384; seg = 1; head = i >> 7; int r = i & 127;
                          qt = r >> 2; piece = r & 3; Lc = 4096; iters = 16; }
    size_t soff = seg == 0 ? 0 : (seg == 1 ? SEG1OFF : SEG2OFF);
    const __bf16* Qh = Qcb + soff + (size_t)head * Lc * 64;
    const __bf16* Kh = Kcb + soff + (size_t)head * Lc * 64;
    const __bf16* Vh = Vtb + soff + (size_t)head * 64 * Lc;
    float* Ob;
    float* Lb;
    if (seg == 0)      { Ob = O0; Lb = L0 + head * 2048; }
    else if (seg == 2) { Ob = O2; Lb = L2 + head * 2048; }
    else {
        Ob = piece == 0 ? O1a : (piece == 1 ? O1b : (piece == 2 ? O1c : O1d));
        Lb = (piece == 0 ? L1a : (piece == 1 ? L1b : (piece == 2 ? L1c : L1d))) + head * 4096;
    }
    int kvb = piece * 16;
    int tid = threadIdx.x, wave = tid >> 6, lane = tid & 63;
    int quad = lane >> 4, l15 = lane & 15;
    bf16x8 qf[2][2];
#pragma unroll
    for (int qg = 0; qg < 2; qg++) {
        size_t qpos = (size_t)(qt * 128 + wave * 32 + qg * 16 + l15);
        qf[qg][0] = *(const bf16x8*)&Qh[qpos * 64 + quad * 8];
        qf[qg][1] = *(const bf16x8*)&Qh[qpos * 64 + 32 + quad * 8];
    }
    f32x4 o[2][4] = {};
    f32x4 lacc[2] = {};
    bf16x8 ones;
#pragma unroll
    for (int j = 0; j < 8; j++) ones[j] = (__bf16)1.0f;
    int kv0 = tid >> 3, cl0 = tid & 7;
    int kdb0 = cl0 ^ (kv0 & 7);
    int kv1 = kv0 + 32, kdb1 = cl0 ^ (kv1 & 7);
    char* KlB = (char*)Kl;
    char* VlB = (char*)Vl;
    int swz = l15 & 7;
    {   // prologue: buffer 0 <- tile kvb; order K,K then V,V (vmcnt ledger)
        int t0 = kvb * 64;
        gl2lds16(&Kh[(size_t)(t0 + kv0) * 64 + kdb0 * 8], KlB + wave * 1024);
        gl2lds16(&Kh[(size_t)(t0 + kv1) * 64 + kdb1 * 8], KlB + 4096 + wave * 1024);
        SCHED_FENCE();
        gl2lds16(&Vh[(size_t)kv0 * Lc + t0 + kdb0 * 8], VlB + wave * 1024);
        gl2lds16(&Vh[(size_t)kv1 * Lc + t0 + kdb1 * 8], VlB + 4096 + wave * 1024);
    }
    for (int nt = 0; nt < iters; nt++) {
        int cur = nt & 1;
        // K-publish: oldest 2 outstanding (this tile's K) must land; V + prefetch fly on
        SCHED_FENCE();
        asm volatile("s_waitcnt vmcnt(2)" ::: "memory");
        __builtin_amdgcn_s_barrier();
        SCHED_FENCE();
        if (nt + 1 < iters) {
            int nb = 8192 * (cur ^ 1);
            int t1 = (kvb + nt + 1) * 64;
            gl2lds16(&Kh[(size_t)(t1 + kv0) * 64 + kdb0 * 8], KlB + nb + wave * 1024);
            gl2lds16(&Kh[(size_t)(t1 + kv1) * 64 + kdb1 * 8], KlB + nb + 4096 + wave * 1024);
            SCHED_FENCE();
            gl2lds16(&Vh[(size_t)kv0 * Lc + t1 + kdb0 * 8], VlB + nb + wave * 1024);
            gl2lds16(&Vh[(size_t)kv1 * Lc + t1 + kdb1 * 8], VlB + nb + 4096 + wave * 1024);
        }
        SCHED_FENCE();
        const __bf16* Kt = Kl + cur * 4096;
        const __bf16* Vt_ = Vl + cur * 4096;
        f32x4 sarr[4][2];
        __builtin_amdgcn_s_setprio(1);
#pragma unroll
        for (int c = 0; c < 4; c++) {
            int krow = (c * 16 + l15) * 64;
            bf16x8 kf0 = *(const bf16x8*)&Kt[krow + ((quad ^ swz) * 8)];
            bf16x8 kf1 = *(const bf16x8*)&Kt[krow + (((4 + quad) ^ swz) * 8)];
#pragma unroll
            for (int qg = 0; qg < 2; qg++) {
                f32x4 z = {};
                z = MFMA_BF16(kf0, qf[qg][0], z);
                sarr[c][qg] = MFMA_BF16(kf1, qf[qg][1], z);
            }
        }
        __builtin_amdgcn_s_setprio(0);
        union { bf16x8 v8; bf16x2 v2[4]; } pf8[2][2];
#pragma unroll
        for (int qg = 0; qg < 2; qg++)
#pragma unroll
            for (int c = 0; c < 4; c++) {
                float p0 = fexp2(sarr[c][qg][0]);
                float p1 = fexp2(sarr[c][qg][1]);
                float p2 = fexp2(sarr[c][qg][2]);
                float p3 = fexp2(sarr[c][qg][3]);
                pf8[qg][c >> 1].v2[(c & 1) * 2 + 0] = pk_bf16(p0, p1);
                pf8[qg][c >> 1].v2[(c & 1) * 2 + 1] = pk_bf16(p2, p3);
            }
        // V-publish: drain this tile's V; prefetched K/V for t+1 stay in flight
        SCHED_FENCE();
        if (nt + 1 < iters) {
            asm volatile("s_waitcnt vmcnt(4)" ::: "memory");
        } else {
            asm volatile("s_waitcnt vmcnt(0)" ::: "memory");
        }
        __builtin_amdgcn_s_barrier();
        SCHED_FENCE();
        __builtin_amdgcn_s_setprio(1);
#pragma unroll
        for (int u = 0; u < 2; u++) {
#pragma unroll
            for (int ds = 0; ds < 4; ds++) {
                int d = ds * 16 + l15;
                bf16x8 vf = *(const bf16x8*)&Vt_[d * 64 + (((u * 4 + quad) ^ swz) * 8)];
                o[0][ds] = MFMA_BF16(vf, pf8[0][u].v8, o[0][ds]);
                o[1][ds] = MFMA_BF16(vf, pf8[1][u].v8, o[1][ds]);
            }
            lacc[0] = MFMA_BF16(ones, pf8[0][u].v8, lacc[0]);
            lacc[1] = MFMA_BF16(ones, pf8[1][u].v8, lacc[1]);
        }
        __builtin_amdgcn_s_setprio(0);
    }
#pragma unroll
    for (int qg = 0; qg < 2; qg++) {
        float l = lacc[qg][0];  // rows redundant: every lane has its column's sum
        int pos = qt * 128 + wave * 32 + qg * 16 + l15;
        float* orow = Ob + (size_t)pos * 768 + head * 64;
#pragma unroll
        for (int ds = 0; ds < 4; ds++)
            *(f32x4*)&orow[ds * 16 + quad * 4] = o[qg][ds];
        if (lane < 16) Lb[qt * 128 + wave * 32 + qg * 16 + lane] = l;
    }
}

// ---------------- combine: attnF[q][768] = (1/3) * sum_seg O_seg/l_seg, bf16 -------
__global__ __launch_bounds__(256) void combine_kernel(
    const float* __restrict__ O0, const float* __restrict__ O1a,
    const float* __restrict__ O1b, const float* __restrict__ O1c,
    const float* __restrict__ O1d, const float* __restrict__ O2,
    const float* __restrict__ L0, const float* __restrict__ L1a,
    const float* __restrict__ L1b, const float* __restrict__ L1c,
    const float* __restrict__ L1d, const float* __restrict__ L2,
    __bf16* __restrict__ attnF) {
    int g = blockIdx.x * 256 + threadIdx.x;  // 8192*96
    int q = g / 96;
    int cs = (g - q * 96) * 8;
    int head = cs >> 6;
    f32x4 a0 = {}, a1 = {};
    if (q < 2048) {
        float inv = 1.0f / L0[head * 2048 + q];
        const f32x4* p = (const f32x4*)&O0[(size_t)q * 768 + cs];
        a0 += p[0] * inv; a1 += p[1] * inv;
    }
    if (!(q & 1)) {
        int p1 = q >> 1;
        int li = head * 4096 + p1;
        float inv = 1.0f / (L1a[li] + L1b[li] + L1c[li] + L1d[li]);
        size_t ro = (size_t)p1 * 768 + cs;
        const f32x4* pa = (const f32x4*)&O1a[ro];
        const f32x4* pb = (const f32x4*)&O1b[ro];
        const f32x4* pc = (const f32x4*)&O1c[ro];
        const f32x4* pd = (const f32x4*)&O1d[ro];
        a0 += ((pa[0] + pb[0]) + (pc[0] + pd[0])) * inv;
        a1 += ((pa[1] + pb[1]) + (pc[1] + pd[1])) * inv;
    }
    if (!(q & 3)) {
        int p2 = q >> 2;
        float inv = 1.0f / L2[head * 2048 + p2];
        const f32x4* p = (const f32x4*)&O2[(size_t)p2 * 768 + cs];
        a0 += p[0] * inv; a1 += p[1] * inv;
    }
    const float third = 1.0f / 3.0f;
    bf16x8 ov;
    ov[0] = (__bf16)(a0[0] * third); ov[1] = (__bf16)(a0[1] * third);
    ov[2] = (__bf16)(a0[2] * third); ov[3] = (__bf16)(a0[3] * third);
    ov[4] = (__bf16)(a1[0] * third); ov[5] = (__bf16)(a1[1] * third);
    ov[6] = (__bf16)(a1[2] * third); ov[7] = (__bf16)(a1[3] * third);
    *(bf16x8*)&attnF[(size_t)q * 768 + cs] = ov;
}

extern "C" void kernel_launch(void* const* d_in, const int* in_sizes, int n_in,
                              void* d_out, int out_size, void* d_ws, size_t ws_size,
                              hipStream_t stream) {
    const float* x    = (const float*)d_in[0];
    const float* Wqkv = (const float*)d_in[1];
    const float* bqkv = (const float*)d_in[2];
    const float* Wout = (const float*)d_in[3];
    const float* bout = (const float*)d_in[4];
    float* out = (float*)d_out;
    (void)in_sizes; (void)n_in; (void)out_size; (void)ws_size;

    char* ws = (char*)d_ws;
    size_t off = 0;
    auto take = [&](size_t bytes) -> void* {
        void* p = ws + off;
        off += (bytes + 255) & ~(size_t)255;
        return p;
    };
    const size_t QKV_ELEMS = (size_t)12 * 8192 * 64;  // compact seg-major total
    __bf16* xb    = (__bf16*)take((size_t)8192 * 768 * 2);  // dead after gemm0 -> O0|O2
    __bf16* WqkvT = (__bf16*)take((size_t)2304 * 768 * 2);
    __bf16* WoutT = (__bf16*)take((size_t)768 * 768 * 2);
    __bf16* Qc    = (__bf16*)take(QKV_ELEMS * 2);           // attnF alias after attn
    __bf16* Kc    = (__bf16*)take(QKV_ELEMS * 2);
    __bf16* Vc    = (__bf16*)take(QKV_ELEMS * 2);           // unused pre-attn -> O1d
    __bf16* Vt    = (__bf16*)take(QKV_ELEMS * 2);
    float*  O1a   = (float*)take((size_t)4096 * 768 * 4);
    float*  O1b   = (float*)take((size_t)4096 * 768 * 4);
    float*  O1c   = (float*)take((size_t)4096 * 768 * 4);
    float*  L0    = (float*)take((size_t)12 * 2048 * 4);
    float*  L1a   = (float*)take((size_t)12 * 4096 * 4);
    float*  L1b   = (float*)take((size_t)12 * 4096 * 4);
    float*  L1c   = (float*)take((size_t)12 * 4096 * 4);
    float*  L1d   = (float*)take((size_t)12 * 4096 * 4);
    float*  L2    = (float*)take((size_t)12 * 2048 * 4);
    float*  O0    = (float*)xb;                 // 2048*768 f32 = 6.29 MB
    float*  O2    = O0 + (size_t)2048 * 768;    // next 6.29 MB (xb is 12.58 MB)
    float*  O1d   = (float*)Vc;                 // 4096*768 f32 = 12.58 MB = |Vc|
    __bf16* attnF = Qc;                         // Qc dead after attn_kernel

    prep_kernel<<<4224, 256, 0, stream>>>(x, Wqkv, Wout, xb, WqkvT, WoutT);
    gemm_qkv_kernel<<<dim3(64, 18), 256, 0, stream>>>(xb, WqkvT, bqkv, Qc, Kc, Vt);
    attn_kernel<<<1920, 256, 0, stream>>>(Qc, Kc, Vt, O0, O1a, O1b, O1c, O1d, O2,
                                          L0, L1a, L1b, L1c, L1d, L2);
    combine_kernel<<<3072, 256, 0, stream>>>(O0, O1a, O1b, O1c, O1d, O2,
                                             L0, L1a, L1b, L1c, L1d, L2, attnF);
    gemm_out_kernel<<<dim3(128, 6), 256, 0, stream>>>(attnF, WoutT, bout, out);
}